// Round 2
// baseline (2766.582 us; speedup 1.0000x reference)
//
#include <hip/hip_runtime.h>

typedef unsigned long long u64;
typedef unsigned int u32;

#define LOGB 22
#define NBUCKETS (1u << LOGB)
#define SCAN_T 256
#define SCAN_E 8
#define SCAN_CHUNK (SCAN_T * SCAN_E)   // 2048
#define MAXB 16

// ---------------- hash + bucket histogram ----------------
__global__ void k_hash_hist(const int* __restrict__ coords, u64* __restrict__ h,
                            u32* __restrict__ hist, int N) {
    int i = blockIdx.x * blockDim.x + threadIdx.x;
    if (i >= N) return;
    u64 hv = 14695981039346656037ull;
    const u64 P = 1099511628211ull;
#pragma unroll
    for (int j = 0; j < 4; j++) {
        hv *= P;
        hv ^= (u64)(long long)coords[i * 4 + j];
    }
    h[i] = hv;
    atomicAdd(&hist[(u32)(hv >> (64 - LOGB))], 1u);
}

// ---------------- generic 2-level scan ----------------
template <bool EXCL>
__global__ void k_scan_chunks(u32* data, int n, u32* sums) {
    __shared__ u32 s[SCAN_T];
    int tid = threadIdx.x;
    int base = blockIdx.x * SCAN_CHUNK;
    int idx0 = base + tid * SCAN_E;
    u32 v[SCAN_E], o[SCAN_E];
    u32 run = 0;
#pragma unroll
    for (int k = 0; k < SCAN_E; k++) {
        int idx = idx0 + k;
        u32 x = (idx < n) ? data[idx] : 0u;
        o[k] = x;
        run += x;
        v[k] = run;
    }
    s[tid] = run;
    __syncthreads();
    for (int off = 1; off < SCAN_T; off <<= 1) {
        u32 t = (tid >= off) ? s[tid - off] : 0u;
        __syncthreads();
        s[tid] += t;
        __syncthreads();
    }
    u32 tbase = s[tid] - run;
#pragma unroll
    for (int k = 0; k < SCAN_E; k++) {
        int idx = idx0 + k;
        if (idx < n) data[idx] = tbase + v[k] - (EXCL ? o[k] : 0u);
    }
    if (tid == SCAN_T - 1 && sums) sums[blockIdx.x] = s[SCAN_T - 1];
}

__global__ void k_scan_single(u32* data, int n) {
    __shared__ u32 s[SCAN_T];
    int tid = threadIdx.x;
    int idx0 = tid * SCAN_E;
    u32 v[SCAN_E], o[SCAN_E];
    u32 run = 0;
#pragma unroll
    for (int k = 0; k < SCAN_E; k++) {
        int idx = idx0 + k;
        u32 x = (idx < n) ? data[idx] : 0u;
        o[k] = x;
        run += x;
        v[k] = run;
    }
    s[tid] = run;
    __syncthreads();
    for (int off = 1; off < SCAN_T; off <<= 1) {
        u32 t = (tid >= off) ? s[tid - off] : 0u;
        __syncthreads();
        s[tid] += t;
        __syncthreads();
    }
    u32 tbase = s[tid] - run;
#pragma unroll
    for (int k = 0; k < SCAN_E; k++) {
        int idx = idx0 + k;
        if (idx < n) data[idx] = tbase + v[k] - o[k];
    }
}

__global__ void k_scan_add(u32* data, int n, const u32* __restrict__ sums) {
    int i = blockIdx.x * blockDim.x + threadIdx.x;
    if (i >= n) return;
    data[i] += sums[i / SCAN_CHUNK];
}

// ---------------- scatter into buckets ----------------
__global__ void k_scatter(const u64* __restrict__ h, u32* __restrict__ offs,
                          u64* __restrict__ key, int* __restrict__ idxs, int N) {
    int i = blockIdx.x * blockDim.x + threadIdx.x;
    if (i >= N) return;
    u64 hv = h[i];
    u32 b = (u32)(hv >> (64 - LOGB));
    u32 pos = atomicAdd(&offs[b], 1u);
    key[pos] = hv;
    idxs[pos] = i;
}

// ---------------- within-bucket sort: in-register Batcher network ----------------
#define CAS(a, b)                                                              \
    {                                                                          \
        if (kk[a] > kk[b] || (kk[a] == kk[b] && ii[a] > ii[b])) {              \
            u64 tk = kk[a]; kk[a] = kk[b]; kk[b] = tk;                         \
            int ti = ii[a]; ii[a] = ii[b]; ii[b] = ti;                         \
        }                                                                      \
    }

__global__ void k_bucket_sort(const u32* __restrict__ offs, u64* __restrict__ key,
                              int* __restrict__ idxs, int B) {
    int b = blockIdx.x * blockDim.x + threadIdx.x;
    if (b >= B) return;
    int end = (int)offs[b];
    int start = b ? (int)offs[b - 1] : 0;
    int size = end - start;
    if (size < 2) return;
    if (size <= MAXB) {
        u64 kk[MAXB];
        int ii[MAXB];
        // independent predicated loads: one memory round trip, not a chain
#pragma unroll
        for (int i = 0; i < MAXB; i++) {
            bool v = i < size;
            kk[i] = v ? key[start + i] : ~0ull;
            ii[i] = v ? idxs[start + i] : 0x7fffffff;
        }
        // Batcher odd-even mergesort, n=16, fully unrolled (static indices)
#pragma unroll
        for (int p = 1; p < MAXB; p <<= 1) {
#pragma unroll
            for (int q = p; q >= 1; q >>= 1) {
#pragma unroll
                for (int j = q % p; j + q < MAXB; j += 2 * q) {
#pragma unroll
                    for (int i = 0; i < q; i++) {
                        if (i + j + q < MAXB) {
                            if ((i + j) / (2 * p) == (i + j + q) / (2 * p)) {
                                CAS(i + j, i + j + q);
                            }
                        }
                    }
                }
            }
        }
#pragma unroll
        for (int i = 0; i < MAXB; i++) {
            if (i < size) {
                key[start + i] = kk[i];
                idxs[start + i] = ii[i];
            }
        }
    } else {
        // fallback (statistically never at these sizes)
        for (int j = start + 1; j < end; j++) {
            u64 kj = key[j];
            int ij = idxs[j];
            int k = j - 1;
            while (k >= start && (key[k] > kj || (key[k] == kj && idxs[k] > ij))) {
                key[k + 1] = key[k];
                idxs[k + 1] = idxs[k];
                k--;
            }
            key[k + 1] = kj;
            idxs[k + 1] = ij;
        }
    }
}

// ---------------- first-occurrence flags ----------------
__global__ void k_first(const u64* __restrict__ key, u32* __restrict__ gid, int N) {
    int i = blockIdx.x * blockDim.x + threadIdx.x;
    if (i >= N) return;
    gid[i] = (i == 0 || key[i] != key[i - 1]) ? 1u : 0u;
}

// ---------------- finalize all outputs ----------------
__global__ void k_finalize(const u32* __restrict__ gid, const int* __restrict__ idxs,
                           const int* __restrict__ coords, const float* __restrict__ feats,
                           float* __restrict__ vox_feats, float* __restrict__ vox_coords,
                           float* __restrict__ v2p, float* __restrict__ nvox, int N, int C) {
    int i = blockIdx.x * blockDim.x + threadIdx.x;
    if (i >= N) return;
    u32 gi = gid[i];
    int g = (int)gi - 1;
    v2p[idxs[i]] = (float)g;
    bool first = (i == 0) || (gid[i - 1] != gi);
    if (first) {
        int p = idxs[i];
#pragma unroll
        for (int c = 0; c < 4; c++) vox_coords[(size_t)g * 4 + c] = (float)coords[p * 4 + c];
        float acc[16];
        for (int c = 0; c < C; c++) acc[c] = 0.0f;
        int j = i;
        int cnt = 0;
        while (j < N && gid[j] == gi) {
            const float* f = &feats[(size_t)idxs[j] * C];
            for (int c = 0; c < C; c++) acc[c] += f[c];
            cnt++;
            j++;
        }
        float fc = (float)cnt;
        for (int c = 0; c < C; c++) vox_feats[(size_t)g * C + c] = acc[c] / fc;
    }
    if (i == N - 1) nvox[0] = (float)gi;
}

extern "C" void kernel_launch(void* const* d_in, const int* in_sizes, int n_in,
                              void* d_out, int out_size, void* d_ws, size_t ws_size,
                              hipStream_t stream) {
    const int* coords = (const int*)d_in[0];
    const float* feats = (const float*)d_in[1];
    int N = in_sizes[0] / 4;
    int C = in_sizes[1] / N;  // 16

    float* out = (float*)d_out;
    float* vox_feats = out;                          // N*C
    float* vox_coords = out + (size_t)N * C;         // N*4
    float* v2p = vox_coords + (size_t)N * 4;         // N
    float* nvox = v2p + (size_t)N;                   // 1

    char* w = (char*)d_ws;
    u64* h = (u64*)w;        w += (size_t)N * 8;
    u64* key = (u64*)w;      w += (size_t)N * 8;
    int* idxs = (int*)w;     w += (size_t)N * 4;
    u32* gid = (u32*)w;      w += (size_t)N * 4;
    u32* offs = (u32*)w;     w += (size_t)NBUCKETS * 4;
    u32* sums = (u32*)w;     w += (size_t)SCAN_CHUNK * 4;

    hipMemsetAsync(offs, 0, (size_t)NBUCKETS * 4, stream);
    hipMemsetAsync(d_out, 0, (size_t)out_size * 4, stream);

    int blocks = (N + 255) / 256;

    k_hash_hist<<<blocks, 256, 0, stream>>>(coords, h, offs, N);

    // exclusive scan over NBUCKETS (in place)
    int bchunks = NBUCKETS / SCAN_CHUNK;  // 2048 (exact)
    k_scan_chunks<true><<<bchunks, SCAN_T, 0, stream>>>(offs, (int)NBUCKETS, sums);
    k_scan_single<<<1, SCAN_T, 0, stream>>>(sums, bchunks);
    k_scan_add<<<(NBUCKETS + 255) / 256, 256, 0, stream>>>(offs, (int)NBUCKETS, sums);

    k_scatter<<<blocks, 256, 0, stream>>>(h, offs, key, idxs, N);
    k_bucket_sort<<<(NBUCKETS + 255) / 256, 256, 0, stream>>>(offs, key, idxs, (int)NBUCKETS);

    k_first<<<blocks, 256, 0, stream>>>(key, gid, N);

    // inclusive scan over N (in place)
    int nchunks = (N + SCAN_CHUNK - 1) / SCAN_CHUNK;
    k_scan_chunks<false><<<nchunks, SCAN_T, 0, stream>>>(gid, N, sums);
    k_scan_single<<<1, SCAN_T, 0, stream>>>(sums, nchunks);
    k_scan_add<<<blocks, 256, 0, stream>>>(gid, N, sums);

    k_finalize<<<blocks, 256, 0, stream>>>(gid, idxs, coords, feats, vox_feats, vox_coords,
                                           v2p, nvox, N, C);
}

// Round 3
// 753.312 us; speedup vs baseline: 3.6726x; 3.6726x over previous
//
#include <hip/hip_runtime.h>

typedef unsigned long long u64;
typedef unsigned int u32;

#define LOGB 22
#define NBUCKETS (1u << LOGB)
#define SCAN_T 256
#define SCAN_E 8
#define SCAN_CHUNK (SCAN_T * SCAN_E)   // 2048
#define SORT_WAVES 4
#define LDS_CAP 512

// ---------------- hash + bucket histogram ----------------
__global__ void k_hash_hist(const int* __restrict__ coords, u64* __restrict__ h,
                            u32* __restrict__ hist, int N) {
    int i = blockIdx.x * blockDim.x + threadIdx.x;
    if (i >= N) return;
    u64 hv = 14695981039346656037ull;
    const u64 P = 1099511628211ull;
#pragma unroll
    for (int j = 0; j < 4; j++) {
        hv *= P;
        hv ^= (u64)(long long)coords[i * 4 + j];
    }
    h[i] = hv;
    atomicAdd(&hist[(u32)(hv >> (64 - LOGB))], 1u);
}

// ---------------- generic 2-level scan ----------------
template <bool EXCL>
__global__ void k_scan_chunks(u32* data, int n, u32* sums) {
    __shared__ u32 s[SCAN_T];
    int tid = threadIdx.x;
    int base = blockIdx.x * SCAN_CHUNK;
    int idx0 = base + tid * SCAN_E;
    u32 v[SCAN_E], o[SCAN_E];
    u32 run = 0;
#pragma unroll
    for (int k = 0; k < SCAN_E; k++) {
        int idx = idx0 + k;
        u32 x = (idx < n) ? data[idx] : 0u;
        o[k] = x;
        run += x;
        v[k] = run;
    }
    s[tid] = run;
    __syncthreads();
    for (int off = 1; off < SCAN_T; off <<= 1) {
        u32 t = (tid >= off) ? s[tid - off] : 0u;
        __syncthreads();
        s[tid] += t;
        __syncthreads();
    }
    u32 tbase = s[tid] - run;
#pragma unroll
    for (int k = 0; k < SCAN_E; k++) {
        int idx = idx0 + k;
        if (idx < n) data[idx] = tbase + v[k] - (EXCL ? o[k] : 0u);
    }
    if (tid == SCAN_T - 1 && sums) sums[blockIdx.x] = s[SCAN_T - 1];
}

__global__ void k_scan_single(u32* data, int n) {
    __shared__ u32 s[SCAN_T];
    int tid = threadIdx.x;
    int idx0 = tid * SCAN_E;
    u32 v[SCAN_E], o[SCAN_E];
    u32 run = 0;
#pragma unroll
    for (int k = 0; k < SCAN_E; k++) {
        int idx = idx0 + k;
        u32 x = (idx < n) ? data[idx] : 0u;
        o[k] = x;
        run += x;
        v[k] = run;
    }
    s[tid] = run;
    __syncthreads();
    for (int off = 1; off < SCAN_T; off <<= 1) {
        u32 t = (tid >= off) ? s[tid - off] : 0u;
        __syncthreads();
        s[tid] += t;
        __syncthreads();
    }
    u32 tbase = s[tid] - run;
#pragma unroll
    for (int k = 0; k < SCAN_E; k++) {
        int idx = idx0 + k;
        if (idx < n) data[idx] = tbase + v[k] - o[k];
    }
}

__global__ void k_scan_add(u32* data, int n, const u32* __restrict__ sums) {
    int i = blockIdx.x * blockDim.x + threadIdx.x;
    if (i >= n) return;
    data[i] += sums[i / SCAN_CHUNK];
}

// ---------------- scatter into buckets ----------------
__global__ void k_scatter(const u64* __restrict__ h, u32* __restrict__ offs,
                          u64* __restrict__ key, int* __restrict__ idxs, int N) {
    int i = blockIdx.x * blockDim.x + threadIdx.x;
    if (i >= N) return;
    u64 hv = h[i];
    u32 b = (u32)(hv >> (64 - LOGB));
    u32 pos = atomicAdd(&offs[b], 1u);
    key[pos] = hv;
    idxs[pos] = i;
}

// ---------------- worklist of buckets needing a sort ----------------
__global__ void k_worklist(const u32* __restrict__ offs, u32* __restrict__ wl,
                           u32* __restrict__ nwork, int B) {
    int b = blockIdx.x * blockDim.x + threadIdx.x;
    if (b >= B) return;
    u32 end = offs[b];
    u32 start = b ? offs[b - 1] : 0u;
    if (end - start >= 2u) {
        u32 p = atomicAdd(nwork, 1u);
        wl[p] = b;
    }
}

// ---------------- one wave per bucket: rank sort ----------------
__global__ void k_bucket_sort_wave(const u32* __restrict__ offs, u64* __restrict__ key,
                                   int* __restrict__ idxs, const u32* __restrict__ wl,
                                   const u32* __restrict__ nwork) {
    __shared__ u64 skey[SORT_WAVES][LDS_CAP];
    __shared__ int sidx[SORT_WAVES][LDS_CAP];
    int w = threadIdx.x >> 6;
    int lane = threadIdx.x & 63;
    int gw = blockIdx.x * SORT_WAVES + w;
    int nw = gridDim.x * SORT_WAVES;
    u32 n = *nwork;
    for (u32 t = (u32)gw; t < n; t += (u32)nw) {
        u32 b = wl[t];
        int end = (int)offs[b];
        int start = b ? (int)offs[b - 1] : 0;
        int s = end - start;
        if (s <= 64) {
            // one element per lane; rank via shfl broadcast
            u64 k = ~0ull;
            int id = 0x7fffffff;
            if (lane < s) {
                k = key[start + lane];
                id = idxs[start + lane];
            }
            int rank = 0;
            for (int j = 0; j < s; j++) {
                u64 kj = __shfl(k, j);
                int ij = __shfl(id, j);
                rank += (kj < k || (kj == k && ij < id)) ? 1 : 0;
            }
            if (lane < s) {
                key[start + rank] = k;
                idxs[start + rank] = id;
            }
        } else if (s <= LDS_CAP) {
            for (int e = lane; e < s; e += 64) {
                skey[w][e] = key[start + e];
                sidx[w][e] = idxs[start + e];
            }
            asm volatile("s_waitcnt lgkmcnt(0)" ::: "memory");
            for (int e = lane; e < s; e += 64) {
                u64 k = skey[w][e];
                int id = sidx[w][e];
                int rank = 0;
                for (int j = 0; j < s; j++) {
                    u64 kj = skey[w][j];
                    int ij = sidx[w][j];
                    rank += (kj < k || (kj == k && ij < id)) ? 1 : 0;
                }
                key[start + rank] = k;
                idxs[start + rank] = id;
            }
            asm volatile("s_waitcnt lgkmcnt(0)" ::: "memory");
        } else {
            // serial fallback (statistically never)
            if (lane == 0) {
                for (int j2 = start + 1; j2 < end; j2++) {
                    u64 kj = key[j2];
                    int ij = idxs[j2];
                    int k2 = j2 - 1;
                    while (k2 >= start && (key[k2] > kj || (key[k2] == kj && idxs[k2] > ij))) {
                        key[k2 + 1] = key[k2];
                        idxs[k2 + 1] = idxs[k2];
                        k2--;
                    }
                    key[k2 + 1] = kj;
                    idxs[k2 + 1] = ij;
                }
            }
        }
    }
}

// ---------------- first-occurrence flags ----------------
__global__ void k_first(const u64* __restrict__ key, u32* __restrict__ gid, int N) {
    int i = blockIdx.x * blockDim.x + threadIdx.x;
    if (i >= N) return;
    gid[i] = (i == 0 || key[i] != key[i - 1]) ? 1u : 0u;
}

// ---------------- finalize all outputs ----------------
__global__ void k_finalize(const u32* __restrict__ gid, const int* __restrict__ idxs,
                           const int* __restrict__ coords, const float* __restrict__ feats,
                           float* __restrict__ vox_feats, float* __restrict__ vox_coords,
                           float* __restrict__ v2p, float* __restrict__ nvox, int N, int C) {
    int i = blockIdx.x * blockDim.x + threadIdx.x;
    if (i >= N) return;
    u32 gi = gid[i];
    int g = (int)gi - 1;
    v2p[idxs[i]] = (float)g;
    bool first = (i == 0) || (gid[i - 1] != gi);
    if (first) {
        int p = idxs[i];
#pragma unroll
        for (int c = 0; c < 4; c++) vox_coords[(size_t)g * 4 + c] = (float)coords[p * 4 + c];
        float4 acc[4];
#pragma unroll
        for (int q = 0; q < 4; q++) acc[q] = make_float4(0.f, 0.f, 0.f, 0.f);
        int j = i;
        int cnt = 0;
        while (j < N && gid[j] == gi) {
            const float4* f = (const float4*)&feats[(size_t)idxs[j] * 16];
#pragma unroll
            for (int q = 0; q < 4; q++) {
                float4 v = f[q];
                acc[q].x += v.x; acc[q].y += v.y; acc[q].z += v.z; acc[q].w += v.w;
            }
            cnt++;
            j++;
        }
        float inv = 1.0f / (float)cnt;
        float4* vf = (float4*)&vox_feats[(size_t)g * 16];
#pragma unroll
        for (int q = 0; q < 4; q++) {
            vf[q] = make_float4(acc[q].x * inv, acc[q].y * inv, acc[q].z * inv, acc[q].w * inv);
        }
    }
    if (i == N - 1) nvox[0] = (float)gi;
}

extern "C" void kernel_launch(void* const* d_in, const int* in_sizes, int n_in,
                              void* d_out, int out_size, void* d_ws, size_t ws_size,
                              hipStream_t stream) {
    const int* coords = (const int*)d_in[0];
    const float* feats = (const float*)d_in[1];
    int N = in_sizes[0] / 4;
    int C = in_sizes[1] / N;  // 16

    float* out = (float*)d_out;
    float* vox_feats = out;                          // N*C
    float* vox_coords = out + (size_t)N * C;         // N*4
    float* v2p = vox_coords + (size_t)N * 4;         // N
    float* nvox = v2p + (size_t)N;                   // 1

    char* w = (char*)d_ws;
    u64* h = (u64*)w;        w += (size_t)N * 8;
    u64* key = (u64*)w;      w += (size_t)N * 8;
    int* idxs = (int*)w;     w += (size_t)N * 4;
    u32* gid = (u32*)w;      w += (size_t)N * 4;
    u32* offs = (u32*)w;     w += (size_t)NBUCKETS * 4;
    u32* sums = (u32*)w;     w += (size_t)SCAN_CHUNK * 4;
    u32* nwork = (u32*)w;    w += 256;
    // worklist aliases h (h is dead after k_scatter, worklist created after)
    u32* wl = (u32*)h;

    hipMemsetAsync(offs, 0, (size_t)NBUCKETS * 4, stream);
    hipMemsetAsync(nwork, 0, 4, stream);
    hipMemsetAsync(d_out, 0, (size_t)out_size * 4, stream);

    int blocks = (N + 255) / 256;

    k_hash_hist<<<blocks, 256, 0, stream>>>(coords, h, offs, N);

    // exclusive scan over NBUCKETS (in place)
    int bchunks = NBUCKETS / SCAN_CHUNK;  // 2048 (exact)
    k_scan_chunks<true><<<bchunks, SCAN_T, 0, stream>>>(offs, (int)NBUCKETS, sums);
    k_scan_single<<<1, SCAN_T, 0, stream>>>(sums, bchunks);
    k_scan_add<<<(NBUCKETS + 255) / 256, 256, 0, stream>>>(offs, (int)NBUCKETS, sums);

    k_scatter<<<blocks, 256, 0, stream>>>(h, offs, key, idxs, N);

    // compact buckets with >=2 elements, then one wave per bucket rank-sort
    k_worklist<<<(NBUCKETS + 255) / 256, 256, 0, stream>>>(offs, wl, nwork, (int)NBUCKETS);
    k_bucket_sort_wave<<<4096, 256, 0, stream>>>(offs, key, idxs, wl, nwork);

    k_first<<<blocks, 256, 0, stream>>>(key, gid, N);

    // inclusive scan over N (in place)
    int nchunks = (N + SCAN_CHUNK - 1) / SCAN_CHUNK;
    k_scan_chunks<false><<<nchunks, SCAN_T, 0, stream>>>(gid, N, sums);
    k_scan_single<<<1, SCAN_T, 0, stream>>>(sums, nchunks);
    k_scan_add<<<blocks, 256, 0, stream>>>(gid, N, sums);

    k_finalize<<<blocks, 256, 0, stream>>>(gid, idxs, coords, feats, vox_feats, vox_coords,
                                           v2p, nvox, N, C);
}

// Round 4
// 432.018 us; speedup vs baseline: 6.4039x; 1.7437x over previous
//
#include <hip/hip_runtime.h>

typedef unsigned long long u64;
typedef unsigned int u32;

#define NTRIP 110592              // 48^3 distinct (c0,c1,c2)
#define TLOG 18
#define TBUCK (1u << TLOG)        // 262144 buckets for the 110K-element sort
#define NBINS (NTRIP * 64)        // 7,077,888 possible point keys
#define SCAN_T 256
#define SCAN_E 8
#define SCAN_CHUNK 2048
#define S2_E 16                   // level-2 pair-scan capacity 4096
#define SORT_WAVES 4
#define LDS_CAP 512

__device__ __forceinline__ u64 fnv3p(int c0, int c1, int c2) {
    u64 h = 14695981039346656037ull;
    const u64 P = 1099511628211ull;
    h *= P; h ^= (u64)c0;
    h *= P; h ^= (u64)c1;
    h *= P; h ^= (u64)c2;
    h *= P;
    return h;  // full hash = this ^ c3  (c3 < 64: flips only low 6 bits)
}

// ======== phase 1: sort the 110,592 triple-hashes, build rank table ========
__global__ void k_tkeys(u64* __restrict__ tkey, u32* __restrict__ thist) {
    int t = blockIdx.x * blockDim.x + threadIdx.x;
    if (t >= NTRIP) return;
    int c0 = t / 2304, r = t % 2304;
    u64 hv = fnv3p(c0, r / 48, r % 48);
    tkey[t] = hv;
    atomicAdd(&thist[(u32)(hv >> (64 - TLOG))], 1u);
}

template <bool EXCL>
__global__ void k_scan_chunks(u32* data, int n, u32* sums) {
    __shared__ u32 s[SCAN_T];
    int tid = threadIdx.x;
    int idx0 = blockIdx.x * SCAN_CHUNK + tid * SCAN_E;
    u32 v[SCAN_E], o[SCAN_E];
    u32 run = 0;
#pragma unroll
    for (int k = 0; k < SCAN_E; k++) {
        int idx = idx0 + k;
        u32 x = (idx < n) ? data[idx] : 0u;
        o[k] = x; run += x; v[k] = run;
    }
    s[tid] = run;
    __syncthreads();
    for (int off = 1; off < SCAN_T; off <<= 1) {
        u32 t = (tid >= off) ? s[tid - off] : 0u;
        __syncthreads();
        s[tid] += t;
        __syncthreads();
    }
    u32 tbase = s[tid] - run;
#pragma unroll
    for (int k = 0; k < SCAN_E; k++) {
        int idx = idx0 + k;
        if (idx < n) data[idx] = tbase + v[k] - (EXCL ? o[k] : 0u);
    }
    if (tid == SCAN_T - 1 && sums) sums[blockIdx.x] = s[SCAN_T - 1];
}

__global__ void k_scan_single(u32* data, int n) {  // exclusive, n <= 2048
    __shared__ u32 s[SCAN_T];
    int tid = threadIdx.x;
    int idx0 = tid * SCAN_E;
    u32 v[SCAN_E], o[SCAN_E];
    u32 run = 0;
#pragma unroll
    for (int k = 0; k < SCAN_E; k++) {
        int idx = idx0 + k;
        u32 x = (idx < n) ? data[idx] : 0u;
        o[k] = x; run += x; v[k] = run;
    }
    s[tid] = run;
    __syncthreads();
    for (int off = 1; off < SCAN_T; off <<= 1) {
        u32 t = (tid >= off) ? s[tid - off] : 0u;
        __syncthreads();
        s[tid] += t;
        __syncthreads();
    }
    u32 tbase = s[tid] - run;
#pragma unroll
    for (int k = 0; k < SCAN_E; k++) {
        int idx = idx0 + k;
        if (idx < n) data[idx] = tbase + v[k] - o[k];
    }
}

__global__ void k_scan_add(u32* data, int n, const u32* __restrict__ sums) {
    int i = blockIdx.x * blockDim.x + threadIdx.x;
    if (i >= n) return;
    data[i] += sums[i / SCAN_CHUNK];
}

__global__ void k_tscatter(const u64* __restrict__ tkey, u32* __restrict__ thist,
                           u64* __restrict__ tsk, u32* __restrict__ tsid) {
    int t = blockIdx.x * blockDim.x + threadIdx.x;
    if (t >= NTRIP) return;
    u64 hv = tkey[t];
    u32 p = atomicAdd(&thist[(u32)(hv >> (64 - TLOG))], 1u);
    tsk[p] = hv;
    tsid[p] = (u32)t;
}

__global__ void k_worklist(const u32* __restrict__ offs, u32* __restrict__ wl,
                           u32* __restrict__ nwork, int B) {
    int b = blockIdx.x * blockDim.x + threadIdx.x;
    if (b >= B) return;
    u32 end = offs[b];
    u32 start = b ? offs[b - 1] : 0u;
    if (end - start >= 2u) {
        u32 p = atomicAdd(nwork, 1u);
        wl[p] = b;
    }
}

__global__ void k_bucket_sort_wave(const u32* __restrict__ offs, u64* __restrict__ key,
                                   int* __restrict__ idxs, const u32* __restrict__ wl,
                                   const u32* __restrict__ nwork) {
    __shared__ u64 skey[SORT_WAVES][LDS_CAP];
    __shared__ int sidx[SORT_WAVES][LDS_CAP];
    int w = threadIdx.x >> 6;
    int lane = threadIdx.x & 63;
    int gw = blockIdx.x * SORT_WAVES + w;
    int nw = gridDim.x * SORT_WAVES;
    u32 n = *nwork;
    for (u32 t = (u32)gw; t < n; t += (u32)nw) {
        u32 b = wl[t];
        int end = (int)offs[b];
        int start = b ? (int)offs[b - 1] : 0;
        int s = end - start;
        if (s <= 64) {
            u64 k = ~0ull;
            int id = 0x7fffffff;
            if (lane < s) { k = key[start + lane]; id = idxs[start + lane]; }
            int rank = 0;
            for (int j = 0; j < s; j++) {
                u64 kj = __shfl(k, j);
                int ij = __shfl(id, j);
                rank += (kj < k || (kj == k && ij < id)) ? 1 : 0;
            }
            if (lane < s) { key[start + rank] = k; idxs[start + rank] = id; }
        } else if (s <= LDS_CAP) {
            for (int e = lane; e < s; e += 64) { skey[w][e] = key[start + e]; sidx[w][e] = idxs[start + e]; }
            asm volatile("s_waitcnt lgkmcnt(0)" ::: "memory");
            for (int e = lane; e < s; e += 64) {
                u64 k = skey[w][e];
                int id = sidx[w][e];
                int rank = 0;
                for (int j = 0; j < s; j++) {
                    u64 kj = skey[w][j];
                    int ij = sidx[w][j];
                    rank += (kj < k || (kj == k && ij < id)) ? 1 : 0;
                }
                key[start + rank] = k;
                idxs[start + rank] = id;
            }
            asm volatile("s_waitcnt lgkmcnt(0)" ::: "memory");
        }
    }
}

__global__ void k_trank(const u64* __restrict__ tsk, const u32* __restrict__ tsid,
                        u32* __restrict__ rank48) {
    int p = blockIdx.x * blockDim.x + threadIdx.x;
    if (p >= NTRIP) return;
    rank48[tsid[p]] = ((u32)p << 6) | (u32)(tsk[p] & 63ull);
}

// ======== phase 2: point keys, histogram, fused pair scan ========
__global__ void k_pkeys(const int* __restrict__ coords, const u32* __restrict__ rank48,
                        u32* __restrict__ pos, int N) {
    int i = blockIdx.x * blockDim.x + threadIdx.x;
    if (i >= N) return;
    int4 c = ((const int4*)coords)[i];
    u32 tau = (u32)c.x * 2304u + (u32)c.y * 48u + (u32)c.z;
    u32 kk = rank48[tau] ^ (u32)c.w;   // == (rank<<6) | ((t&63)^c3)
    atomicAdd(&pos[kk], 1u);
}

// pos: counts -> exclusive scan (in place); gidmap: inclusive occupancy scan.
// lvl2[blk] = (flagsum<<32) | cntsum. Grid exactly NBINS/SCAN_CHUNK.
__global__ void k_scan2(u32* __restrict__ pos, u32* __restrict__ gidmap, u64* __restrict__ lvl2) {
    __shared__ u64 s[SCAN_T];
    int tid = threadIdx.x;
    int base = blockIdx.x * SCAN_CHUNK + tid * SCAN_E;
    u32 cv[SCAN_E];
    u64 incl[SCAN_E];
    u64 run = 0;
#pragma unroll
    for (int e = 0; e < SCAN_E; e++) {
        u32 c = pos[base + e];
        cv[e] = c;
        run += (u64)c | ((u64)(c ? 1u : 0u) << 32);
        incl[e] = run;
    }
    s[tid] = run;
    __syncthreads();
    for (int off = 1; off < SCAN_T; off <<= 1) {
        u64 t = (tid >= off) ? s[tid - off] : 0;
        __syncthreads();
        s[tid] += t;
        __syncthreads();
    }
    u64 tbase = s[tid] - run;
#pragma unroll
    for (int e = 0; e < SCAN_E; e++) {
        u64 v = tbase + incl[e];
        pos[base + e] = (u32)v - cv[e];       // exclusive count-scan
        gidmap[base + e] = (u32)(v >> 32);    // inclusive flag-scan
    }
    if (tid == SCAN_T - 1) lvl2[blockIdx.x] = s[SCAN_T - 1];
}

__global__ void k_scan2_single(u64* data, int n) {  // exclusive, n <= 4096
    __shared__ u64 s[SCAN_T];
    int tid = threadIdx.x;
    int idx0 = tid * S2_E;
    u64 v[S2_E], o[S2_E];
    u64 run = 0;
#pragma unroll
    for (int k = 0; k < S2_E; k++) {
        int idx = idx0 + k;
        u64 x = (idx < n) ? data[idx] : 0;
        o[k] = x; run += x; v[k] = run;
    }
    s[tid] = run;
    __syncthreads();
    for (int off = 1; off < SCAN_T; off <<= 1) {
        u64 t = (tid >= off) ? s[tid - off] : 0;
        __syncthreads();
        s[tid] += t;
        __syncthreads();
    }
    u64 tbase = s[tid] - run;
#pragma unroll
    for (int k = 0; k < S2_E; k++) {
        int idx = idx0 + k;
        if (idx < n) data[idx] = tbase + v[k] - o[k];
    }
}

__global__ void k_scan2_add(u32* __restrict__ pos, u32* __restrict__ gidmap,
                            const u64* __restrict__ lvl2) {
    int i = blockIdx.x * blockDim.x + threadIdx.x;
    if (i >= NBINS) return;
    u64 pr = lvl2[i / SCAN_CHUNK];
    pos[i] += (u32)pr;
    gidmap[i] += (u32)(pr >> 32);
}

// ======== phase 3: per-point gid/v2p + index scatter ========
__global__ void k_points2(const int* __restrict__ coords, const u32* __restrict__ rank48,
                          const u32* __restrict__ gidmap, u32* __restrict__ pos,
                          u32* __restrict__ sortedidx, float* __restrict__ v2p, int N) {
    int i = blockIdx.x * blockDim.x + threadIdx.x;
    if (i >= N) return;
    int4 c = ((const int4*)coords)[i];
    u32 tau = (u32)c.x * 2304u + (u32)c.y * 48u + (u32)c.z;
    u32 kk = rank48[tau] ^ (u32)c.w;
    v2p[i] = (float)(gidmap[kk] - 1u);
    u32 p = atomicAdd(&pos[kk], 1u);
    sortedidx[p] = (u32)i;
}

// ======== phase 4: per-voxel mean + coords (deterministic id-order sum) ========
__global__ void k_vox(const u32* __restrict__ pos, const u32* __restrict__ gidmap,
                      const u32* __restrict__ sortedidx, const int* __restrict__ coords,
                      const float* __restrict__ feats, float* __restrict__ vox_feats,
                      float* __restrict__ vox_coords) {
    int k = blockIdx.x * blockDim.x + threadIdx.x;
    if (k >= NBINS) return;
    u32 endv = pos[k];                    // after scatter: inclusive scan value
    u32 start = k ? pos[k - 1] : 0u;      // neighbor = this bin's start
    u32 c = endv - start;
    if (!c) return;
    u32 gid = gidmap[k] - 1u;
    float4 a0 = {0, 0, 0, 0}, a1 = {0, 0, 0, 0}, a2 = {0, 0, 0, 0}, a3 = {0, 0, 0, 0};
    int last = -1, minid = 0x7fffffff;
    for (u32 it = 0; it < c; it++) {
        int mn = 0x7fffffff;
        for (u32 j = 0; j < c; j++) {
            int id = (int)sortedidx[start + j];
            if (id > last && id < mn) mn = id;
        }
        last = mn;
        if (it == 0) minid = mn;
        const float4* f = (const float4*)(feats + (size_t)mn * 16);
        float4 v0 = f[0], v1 = f[1], v2 = f[2], v3 = f[3];
        a0.x += v0.x; a0.y += v0.y; a0.z += v0.z; a0.w += v0.w;
        a1.x += v1.x; a1.y += v1.y; a1.z += v1.z; a1.w += v1.w;
        a2.x += v2.x; a2.y += v2.y; a2.z += v2.z; a2.w += v2.w;
        a3.x += v3.x; a3.y += v3.y; a3.z += v3.z; a3.w += v3.w;
    }
    float fc = (float)c;
    float4* vf = (float4*)(vox_feats + (size_t)gid * 16);
    vf[0] = make_float4(a0.x / fc, a0.y / fc, a0.z / fc, a0.w / fc);
    vf[1] = make_float4(a1.x / fc, a1.y / fc, a1.z / fc, a1.w / fc);
    vf[2] = make_float4(a2.x / fc, a2.y / fc, a2.z / fc, a2.w / fc);
    vf[3] = make_float4(a3.x / fc, a3.y / fc, a3.z / fc, a3.w / fc);
    int4 cc = ((const int4*)coords)[minid];
    *(float4*)(vox_coords + (size_t)gid * 4) =
        make_float4((float)cc.x, (float)cc.y, (float)cc.z, (float)cc.w);
}

// ======== phase 5: zero padding rows, write num_voxels ========
__global__ void k_zero(const u32* __restrict__ gidmap, float* __restrict__ vox_feats,
                       float* __restrict__ vox_coords, float* __restrict__ nvox, int N) {
    int i = blockIdx.x * blockDim.x + threadIdx.x;
    if (i >= N) return;
    u32 nv = gidmap[NBINS - 1];
    if ((u32)i >= nv) {
        float4 z = {0, 0, 0, 0};
        float4* vf = (float4*)(vox_feats + (size_t)i * 16);
        vf[0] = z; vf[1] = z; vf[2] = z; vf[3] = z;
        *(float4*)(vox_coords + (size_t)i * 4) = z;
    }
    if (i == 0) nvox[0] = (float)nv;
}

extern "C" void kernel_launch(void* const* d_in, const int* in_sizes, int n_in,
                              void* d_out, int out_size, void* d_ws, size_t ws_size,
                              hipStream_t stream) {
    const int* coords = (const int*)d_in[0];
    const float* feats = (const float*)d_in[1];
    int N = in_sizes[0] / 4;

    float* out = (float*)d_out;
    float* vox_feats = out;                      // N*16
    float* vox_coords = out + (size_t)N * 16;    // N*4
    float* v2p = vox_coords + (size_t)N * 4;     // N
    float* nvox = v2p + (size_t)N;               // 1

    char* w = (char*)d_ws;
    u32* pos = (u32*)w;       w += (size_t)NBINS * 4;
    u32* gidmap = (u32*)w;    w += (size_t)NBINS * 4;
    u32* sortedidx = (u32*)w; w += (size_t)N * 4;
    u32* rank48 = (u32*)w;    w += (size_t)NTRIP * 4;
    u64* lvl2 = (u64*)w;      w += 4096 * 8;
    u32* sums32 = (u32*)w;    w += 2048 * 4;
    u32* nwork = (u32*)w;     w += 256;
    // triple-phase scratch aliases gidmap (gidmap first written in k_scan2, after phase 1)
    char* g = (char*)gidmap;
    u64* tkey = (u64*)g;
    u64* tsk = (u64*)(g + 884736);
    u32* tsid = (u32*)(g + 1769472);
    u32* thist = (u32*)(g + 2211840);
    u32* twl = (u32*)(g + 3260416);

    hipMemsetAsync(pos, 0, (size_t)NBINS * 4, stream);
    hipMemsetAsync(thist, 0, (size_t)TBUCK * 4, stream);
    hipMemsetAsync(nwork, 0, 4, stream);

    int blocksN = (N + 255) / 256;
    int blocksT = (NTRIP + 255) / 256;

    // phase 1: rank table for the 110,592 triple-hashes
    k_tkeys<<<blocksT, 256, 0, stream>>>(tkey, thist);
    k_scan_chunks<true><<<TBUCK / SCAN_CHUNK, SCAN_T, 0, stream>>>(thist, (int)TBUCK, sums32);
    k_scan_single<<<1, SCAN_T, 0, stream>>>(sums32, TBUCK / SCAN_CHUNK);
    k_scan_add<<<TBUCK / 256, 256, 0, stream>>>(thist, (int)TBUCK, sums32);
    k_tscatter<<<blocksT, 256, 0, stream>>>(tkey, thist, tsk, tsid);
    k_worklist<<<TBUCK / 256, 256, 0, stream>>>(thist, twl, nwork, (int)TBUCK);
    k_bucket_sort_wave<<<2048, 256, 0, stream>>>(thist, tsk, (int*)tsid, twl, nwork);
    k_trank<<<blocksT, 256, 0, stream>>>(tsk, tsid, rank48);

    // phase 2: point-key histogram + fused pair scan
    k_pkeys<<<blocksN, 256, 0, stream>>>(coords, rank48, pos, N);
    k_scan2<<<NBINS / SCAN_CHUNK, SCAN_T, 0, stream>>>(pos, gidmap, lvl2);
    k_scan2_single<<<1, SCAN_T, 0, stream>>>(lvl2, NBINS / SCAN_CHUNK);
    k_scan2_add<<<NBINS / 256, 256, 0, stream>>>(pos, gidmap, lvl2);

    // phase 3: v2p + index scatter
    k_points2<<<blocksN, 256, 0, stream>>>(coords, rank48, gidmap, pos, sortedidx, v2p, N);

    // phase 4: per-voxel outputs
    k_vox<<<NBINS / 256, 256, 0, stream>>>(pos, gidmap, sortedidx, coords, feats,
                                           vox_feats, vox_coords);

    // phase 5: zero padding rows + num_voxels
    k_zero<<<blocksN, 256, 0, stream>>>(gidmap, vox_feats, vox_coords, nvox, N);
}